// Round 1
// baseline (269.426 us; speedup 1.0000x reference)
//
#include <hip/hip_runtime.h>
#include <stdint.h>

#define NUM_E 50000
#define EMBED_DIM 128
#define HID_DIM 200
#define BATCH 512
#define NN 50
#define KPAD 224
#define NKT 7      // K tiles of 32 for scores GEMM
#define NTT2 3136  // N fragment tiles padded: 3136*16 = 50176 = 196*256
#define NXB 196
#define PACK_UNITS 784
#define USTRIDE 201

typedef short s16x8 __attribute__((ext_vector_type(8)));
typedef float f32x4 __attribute__((ext_vector_type(4)));

__device__ inline unsigned short f2bf(float f) {
  union { float f; unsigned u; } v; v.f = f;
  unsigned r = v.u + 0x7FFF + ((v.u >> 16) & 1);
  return (unsigned short)(r >> 16);
}
__device__ inline float bf2f(unsigned short b) {
  union { unsigned u; float f; } v; v.u = ((unsigned)b) << 16;
  return v.f;
}

// ---------------------------------------------------------------------------
// scores-GEMM tile (64M x 256N, K=224) — direct-to-register B loads.
// Each wave owns 4 n-tiles; B fragments are consumed only by the wave that
// loads them, so there is no LDS staging and NO barrier in the k-loop.
// red: 256 floats LDS (PASS0 partials / PASS1 invD+invS broadcast).
// ---------------------------------------------------------------------------
template<int PASS>
__device__ __forceinline__ void gemm_tile(
    int yb, int xb, float* red, int tid,
    const unsigned short* Ap, const unsigned short* Bp, const float* mlp_b,
    const float* D_ws, float* S_ws, float* out)
{
  const int w = tid >> 6, lane = tid & 63;
  const int q = lane >> 4, l15 = lane & 15;
  const int mt0 = yb * 4;
  const int m0 = yb * 64;
  const int ntb = xb * 16 + w * 4;

  if (PASS == 1 && tid < 64) {
    red[tid]      = 0.5f / D_ws[m0 + tid];
    red[64 + tid] = 0.5f / S_ws[m0 + tid];
  }
  float bias[4];
  #pragma unroll
  for (int nl = 0; nl < 4; ++nl) {
    const int col = (ntb + nl) * 16 + l15;
    bias[nl] = (col < NUM_E) ? mlp_b[col] : 0.f;
  }
  const unsigned short* apB = Ap + (size_t)mt0 * NKT * 512 + (size_t)lane * 8;
  const unsigned short* bpB = Bp + (size_t)ntb * NKT * 512 + (size_t)lane * 8;

  f32x4 acc[4][4];
  #pragma unroll
  for (int i = 0; i < 4; i++)
    #pragma unroll
    for (int j = 0; j < 4; j++) acc[i][j] = (f32x4){0, 0, 0, 0};

  #pragma unroll
  for (int kt = 0; kt < NKT; ++kt) {
    s16x8 a[4], b[4];
    #pragma unroll
    for (int mi = 0; mi < 4; ++mi)
      a[mi] = *(const s16x8*)(apB + (size_t)(mi * NKT + kt) * 512);
    #pragma unroll
    for (int nl = 0; nl < 4; ++nl)
      b[nl] = *(const s16x8*)(bpB + (size_t)(nl * NKT + kt) * 512);
    #pragma unroll
    for (int nl = 0; nl < 4; ++nl)
      #pragma unroll
      for (int mi = 0; mi < 4; ++mi)
        acc[mi][nl] = __builtin_amdgcn_mfma_f32_16x16x32_bf16(a[mi], b[nl], acc[mi][nl], 0, 0, 0);
  }

  if (PASS == 0) {
    float rs[4][4];
    #pragma unroll
    for (int mi = 0; mi < 4; mi++)
      #pragma unroll
      for (int p = 0; p < 4; p++) rs[mi][p] = 0.f;
    #pragma unroll
    for (int mi = 0; mi < 4; ++mi)
      #pragma unroll
      for (int nl = 0; nl < 4; ++nl) {
        const int col = (ntb + nl) * 16 + l15;
        #pragma unroll
        for (int p = 0; p < 4; p++) {
          const float v = acc[mi][nl][p] + bias[nl];
          rs[mi][p] += (col < NUM_E) ? __expf(v) : 0.f;
        }
      }
    #pragma unroll
    for (int m = 1; m < 16; m <<= 1)
      for (int mi = 0; mi < 4; mi++)
        for (int p = 0; p < 4; p++)
          rs[mi][p] += __shfl_xor(rs[mi][p], m, 64);
    if (l15 == 0)
      for (int mi = 0; mi < 4; mi++)
        for (int p = 0; p < 4; p++)
          red[w * 64 + mi * 16 + q * 4 + p] = rs[mi][p];
    __syncthreads();
    if (tid < 64)
      atomicAdd(&S_ws[m0 + tid],
                red[tid] + red[64 + tid] + red[128 + tid] + red[192 + tid]);
  } else {
    __syncthreads();  // publish red[] (invD/invS) written by wave 0
    #pragma unroll
    for (int mi = 0; mi < 4; ++mi) {
      #pragma unroll
      for (int p = 0; p < 4; p++) {
        const int rl = mi * 16 + q * 4 + p;
        const float invD = red[rl];
        const float invS = red[64 + rl];
        const int row = m0 + rl;
        #pragma unroll
        for (int nl = 0; nl < 4; ++nl) {
          const int col = (ntb + nl) * 16 + l15;
          if (col < NUM_E) {
            const float v = acc[mi][nl][p] + bias[nl];
            out[(size_t)row * NUM_E + col] = __logf(fmaf(__expf(v), invS, invD));
          }
        }
      }
    }
  }
}

// ---------------------------------------------------------------------------
// Stage 1: grid = 512 batch blocks (fused xgemm+routing, one block per batch
// row) + 784 pack blocks (mlp_w -> Bp fragments) + 1 S-zero block.
// ---------------------------------------------------------------------------
__global__ __launch_bounds__(256, 3) void k_stage1(
    const int* __restrict__ idx, const int* __restrict__ times,
    const float* __restrict__ emb, const float* __restrict__ Ws_w,
    const float* __restrict__ Ws_b, const float* __restrict__ mlp_w,
    unsigned short* __restrict__ Bp, unsigned short* __restrict__ Ap,
    float* __restrict__ poses_f, float* __restrict__ expa_ws,
    float* __restrict__ D_ws, float* __restrict__ S_ws)
{
  __shared__ __align__(16) char buf[40320];
  __shared__ float cc[NN], bb[NN], vv[HID_DIM], red4[4], scaleS;
  __shared__ int sidx[NN];
  const int u = blockIdx.x;
  const int tid = threadIdx.x;
  const int w = tid >> 6, lane = tid & 63;
  const int q = lane >> 4, l15 = lane & 15;

  if (u < BATCH) {
    // ================= fused xgemm + routing for batch row u ==============
    const int b = u;
    if (tid < NN) {
      sidx[tid] = idx[b * NN + tid];
      bb[tid] = 2.0f / (1.0f + (float)times[b * NN + tid]);
    }
    __syncthreads();
    unsigned short* Afr = (unsigned short*)buf;            // 16384 B
    unsigned short* Bfr = (unsigned short*)(buf + 16384);  // 13312 B per kt
    // stage A fragments: 64 rows (>=NN zero) x 128 k, gather from emb
    for (int v = tid; v < 1024; v += 256) {
      const int row = v >> 4, c = v & 15;
      const int kt = c >> 2, qq = c & 3;
      unsigned short tmp[8] __attribute__((aligned(16)));
      if (row < NN) {
        const float* src = emb + (size_t)sidx[row] * EMBED_DIM + c * 8;
        float4 f0 = *(const float4*)src;
        float4 f1 = *(const float4*)(src + 4);
        tmp[0] = f2bf(f0.x); tmp[1] = f2bf(f0.y); tmp[2] = f2bf(f0.z); tmp[3] = f2bf(f0.w);
        tmp[4] = f2bf(f1.x); tmp[5] = f2bf(f1.y); tmp[6] = f2bf(f1.z); tmp[7] = f2bf(f1.w);
      } else {
        for (int j = 0; j < 8; j++) tmp[j] = 0;
      }
      *(uint4*)&Afr[(((row >> 4) * 4 + kt) * 64 + qq * 16 + (row & 15)) * 8] = *(uint4*)tmp;
    }
    f32x4 acc[4][4];
    #pragma unroll
    for (int i = 0; i < 4; i++)
      #pragma unroll
      for (int j = 0; j < 4; j++) acc[i][j] = (f32x4){0, 0, 0, 0};
    __syncthreads();
    for (int kt = 0; kt < 4; ++kt) {
      // stage B kt-slice: 208 n (>=HID zero) x 32 k from Ws_w
      for (int v = tid; v < 832; v += 256) {
        const int n = v >> 2, cq = v & 3;
        unsigned short tmp[8] __attribute__((aligned(16)));
        if (n < HID_DIM) {
          const float* src = Ws_w + (size_t)n * EMBED_DIM + kt * 32 + cq * 8;
          float4 f0 = *(const float4*)src;
          float4 f1 = *(const float4*)(src + 4);
          tmp[0] = f2bf(f0.x); tmp[1] = f2bf(f0.y); tmp[2] = f2bf(f0.z); tmp[3] = f2bf(f0.w);
          tmp[4] = f2bf(f1.x); tmp[5] = f2bf(f1.y); tmp[6] = f2bf(f1.z); tmp[7] = f2bf(f1.w);
        } else {
          for (int j = 0; j < 8; j++) tmp[j] = 0;
        }
        *(uint4*)&Bfr[((n >> 4) * 64 + cq * 16 + (n & 15)) * 8] = *(uint4*)tmp;
      }
      __syncthreads();
      s16x8 a[4];
      #pragma unroll
      for (int mt = 0; mt < 4; ++mt)
        a[mt] = *(const s16x8*)&Afr[((mt * 4 + kt) * 64 + lane) * 8];
      #pragma unroll
      for (int ii = 0; ii < 4; ++ii) {
        const int nt = w + ii * 4;
        if (nt < 13) {
          s16x8 bv = *(const s16x8*)&Bfr[(nt * 64 + lane) * 8];
          #pragma unroll
          for (int mt = 0; mt < 4; ++mt)
            acc[mt][ii] = __builtin_amdgcn_mfma_f32_16x16x32_bf16(a[mt], bv, acc[mt][ii], 0, 0, 0);
        }
      }
      __syncthreads();
    }
    // epilogue: x = acc + Ws_b into u-matrix (fp32, overlays frag LDS)
    float* uu = (float*)buf;
    #pragma unroll
    for (int ii = 0; ii < 4; ++ii) {
      const int nt = w + ii * 4;
      if (nt < 13) {
        const int col = nt * 16 + l15;
        if (col < HID_DIM) {
          const float bv = Ws_b[col];
          #pragma unroll
          for (int mt = 0; mt < 4; ++mt)
            #pragma unroll
            for (int p = 0; p < 4; p++) {
              const int row = mt * 16 + q * 4 + p;
              if (row < NN) uu[row * USTRIDE + col] = acc[mt][ii][p] + bv;
            }
        }
      }
    }
    __syncthreads();
    // L2-normalize rows (4 threads/row)
    const int un = tid >> 2, uc0 = (tid & 3) * 50;
    if (un < NN) {
      float s = 0.f;
      for (int j = 0; j < 50; j++) {
        const float x = uu[un * USTRIDE + uc0 + j];
        s += x * x;
      }
      s += __shfl_xor(s, 1, 64);
      s += __shfl_xor(s, 2, 64);
      const float inv = 1.0f / fmaxf(sqrtf(s), 1e-12f);
      for (int j = 0; j < 50; j++) uu[un * USTRIDE + uc0 + j] *= inv;
    }
    __syncthreads();
    // dynamic routing, 3 iters
    for (int it = 0; it < 3; ++it) {
      if (tid < 64) {
        float x = (tid < NN) ? bb[tid] : -1e30f;
        float m = x;
        for (int d = 1; d < 64; d <<= 1) m = fmaxf(m, __shfl_xor(m, d, 64));
        float e = (tid < NN) ? __expf(x - m) : 0.f;
        float s = e;
        for (int d = 1; d < 64; d <<= 1) s += __shfl_xor(s, d, 64);
        if (tid < NN) cc[tid] = e * (float)NN / s;
      }
      __syncthreads();
      float sh = 0.f;
      if (tid < HID_DIM)
        for (int n = 0; n < NN; n++) sh += cc[n] * uu[n * USTRIDE + tid];
      float sq2 = (tid < HID_DIM) ? sh * sh : 0.f;
      for (int d = 1; d < 64; d <<= 1) sq2 += __shfl_xor(sq2, d, 64);
      if ((tid & 63) == 0) red4[tid >> 6] = sq2;
      __syncthreads();
      if (tid == 0) {
        const float t2 = red4[0] + red4[1] + red4[2] + red4[3];
        scaleS = t2 / (1.0f + t2) / sqrtf(t2 + 1e-9f);
      }
      __syncthreads();
      if (tid < HID_DIM) vv[tid] = scaleS * sh;
      __syncthreads();
      if (it < 2) {
        float d = 0.f;
        if (un < NN)
          for (int j = 0; j < 50; j++)
            d += uu[un * USTRIDE + uc0 + j] * vv[uc0 + j];
        d += __shfl_xor(d, 1, 64);
        d += __shfl_xor(d, 2, 64);
        if (un < NN && (tid & 3) == 0) bb[un] += d;
        __syncthreads();
      }
    }
    // outputs: Ap fragments, fp32 poses, expa, D_b
    if (tid < KPAD) {
      const float val = (tid < HID_DIM) ? vv[tid] : 0.f;
      const int kt = tid >> 5, rem = tid & 31, qq = rem >> 3, j = rem & 7;
      const int mt = b >> 4, ll = b & 15;
      Ap[(size_t)(((mt * NKT + kt) * 64) + qq * 16 + ll) * 8 + j] = f2bf(val);
    }
    if (tid < HID_DIM) poses_f[b * HID_DIM + tid] = vv[tid];
    if (tid < 64) {
      float a2 = 0.f; int first = 1;
      const int my = (tid < NN) ? sidx[tid] : -1;
      if (tid < NN) {
        for (int n = 0; n < NN; n++)
          if (sidx[n] == my) { a2 += cc[n]; if (n < tid) first = 0; }
        expa_ws[b * NN + tid] = __expf(a2);
      }
      float contrib = (tid < NN && first) ? (__expf(a2) - 1.0f) : 0.f;
      for (int d = 1; d < 64; d <<= 1) contrib += __shfl_xor(contrib, d, 64);
      if (tid == 0) D_ws[b] = (float)NUM_E + contrib;
    }
  } else if (u < BATCH + PACK_UNITS) {
    // ================= coalesced pack of 4 n-tiles into Bp =================
    const int pb = u - BATCH;
    unsigned short* smem = (unsigned short*)buf;
    const size_t base_f = (size_t)pb * 64 * HID_DIM;
    const float4* src4 = (const float4*)(mlp_w + base_f);
    for (int i = tid; i < 3200; i += 256) {
      float4 f;
      if (base_f + 4 * (size_t)i + 4 <= (size_t)NUM_E * HID_DIM) f = src4[i];
      else f = make_float4(0.f, 0.f, 0.f, 0.f);
      unsigned short t4[4] __attribute__((aligned(8))) = {
        f2bf(f.x), f2bf(f.y), f2bf(f.z), f2bf(f.w)};
      *(uint2*)&smem[i * 4] = *(uint2*)t4;
    }
    __syncthreads();
    const int nt0 = pb * 4;
    unsigned short* dst = Bp + (size_t)nt0 * NKT * 512;
    for (int s2 = 0; s2 < 7; ++s2) {
      const int fi = s2 * 256 + tid;
      const int fr = fi >> 6;
      const int ln = fi & 63;
      const int nt_l = fr / 7, kt = fr - nt_l * 7;
      const int r = nt_l * 16 + (ln & 15);
      const int kb = kt * 32 + (ln >> 4) * 8;
      uint4 val;
      if (kb < HID_DIM) val = *(const uint4*)&smem[r * HID_DIM + kb];
      else val = make_uint4(0, 0, 0, 0);
      *(uint4*)&dst[(size_t)fi * 8] = val;
    }
  } else {
    S_ws[tid] = 0.f;
    S_ws[256 + tid] = 0.f;
  }
}

// ---------------------------------------------------------------------------
// Kernel G: XCD-swizzled 1-D grid of 1600: xb = id % 200 (skip >= 196),
// yb = id / 200. Stride 200 == 0 mod 8 keeps a Bp column-slice on one XCD.
// ---------------------------------------------------------------------------
template<int PASS>
__global__ __launch_bounds__(256, 4) void k_gemm(
    const unsigned short* __restrict__ Ap, const unsigned short* __restrict__ Bp,
    const float* __restrict__ mlp_b, const float* __restrict__ D_ws,
    float* __restrict__ S_ws, float* __restrict__ out)
{
  __shared__ float red[256];
  const int id = blockIdx.x;
  const int yb = id / 200;
  const int xb = id - yb * 200;
  if (xb >= NXB) return;
  gemm_tile<PASS>(yb, xb, red, threadIdx.x, Ap, Bp, mlp_b, D_ws, S_ws, out);
}

// ---------------------------------------------------------------------------
// Kernel D: fixup history positions; recompute score via fp32 dot product.
// ---------------------------------------------------------------------------
__global__ __launch_bounds__(256) void k_fix(
    const int* __restrict__ idx, const float* __restrict__ expa,
    const float* __restrict__ poses_f, const float* __restrict__ mlp_w,
    const float* __restrict__ mlp_b, const float* __restrict__ D_ws,
    const float* __restrict__ S_ws, float* __restrict__ out)
{
  const int t = blockIdx.x * 4 + (threadIdx.x >> 6);
  const int lane = threadIdx.x & 63;
  if (t >= BATCH * NN) return;
  const int b = t / NN;
  const int j = idx[t];
  float dot = 0.f;
  for (int h = lane; h < HID_DIM; h += 64)
    dot += poses_f[b * HID_DIM + h] * mlp_w[(size_t)j * HID_DIM + h];
  for (int m = 1; m < 64; m <<= 1) dot += __shfl_xor(dot, m, 64);
  if (lane == 0) {
    const float s = dot + mlp_b[j];
    out[(size_t)b * NUM_E + j] = __logf(0.5f * expa[t] / D_ws[b] +
                                        0.5f * __expf(s) / S_ws[b]);
  }
}

extern "C" void kernel_launch(void* const* d_in, const int* in_sizes, int n_in,
                              void* d_out, int out_size, void* d_ws, size_t ws_size,
                              hipStream_t stream) {
  const int*   idx   = (const int*)d_in[0];
  const int*   times = (const int*)d_in[1];
  const float* emb   = (const float*)d_in[2];
  const float* Ws_w  = (const float*)d_in[3];
  const float* Ws_b  = (const float*)d_in[4];
  const float* mlp_w = (const float*)d_in[5];
  const float* mlp_b = (const float*)d_in[6];
  float* out = (float*)d_out;

  char* ws = (char*)d_ws;
  unsigned short* Bp    = (unsigned short*)ws; ws += (size_t)NTT2 * NKT * 64 * 8 * 2;  // 22.5 MB
  unsigned short* Ap    = (unsigned short*)ws; ws += (size_t)32 * NKT * 64 * 8 * 2;    // 229 KB
  float* poses_f        = (float*)ws;          ws += (size_t)BATCH * HID_DIM * 4;      // 410 KB
  float* expa           = (float*)ws;          ws += (size_t)BATCH * NN * 4;           // 102 KB
  float* D_ws           = (float*)ws;          ws += (size_t)BATCH * 4;
  float* S_ws           = (float*)ws;          ws += (size_t)BATCH * 4;

  k_stage1 <<<dim3(BATCH + PACK_UNITS + 1), 256, 0, stream>>>(
      idx, times, emb, Ws_w, Ws_b, mlp_w, Bp, Ap, poses_f, expa, D_ws, S_ws);
  k_gemm<0><<<dim3(1600),           256, 0, stream>>>(Ap, Bp, mlp_b, D_ws, S_ws, out);
  k_gemm<1><<<dim3(1600),           256, 0, stream>>>(Ap, Bp, mlp_b, D_ws, S_ws, out);
  k_fix    <<<dim3(BATCH * NN / 4), 256, 0, stream>>>(idx, expa, poses_f, mlp_w, mlp_b, D_ws, S_ws, out);
}

// Round 3
// 265.161 us; speedup vs baseline: 1.0161x; 1.0161x over previous
//
#include <hip/hip_runtime.h>
#include <stdint.h>

#define NUM_E 50000
#define EMBED_DIM 128
#define HID_DIM 200
#define BATCH 512
#define NN 50
#define KPAD 224
#define NKT 7      // K tiles of 32 for scores GEMM
#define NTT2 3136  // N fragment tiles padded: 3136*16 = 50176 = 196*256
#define NXB 196
#define PACK_UNITS 784
#define USTRIDE 201

typedef short s16x8 __attribute__((ext_vector_type(8)));
typedef float f32x4 __attribute__((ext_vector_type(4)));

__device__ inline unsigned short f2bf(float f) {
  union { float f; unsigned u; } v; v.f = f;
  unsigned r = v.u + 0x7FFF + ((v.u >> 16) & 1);
  return (unsigned short)(r >> 16);
}
__device__ inline float bf2f(unsigned short b) {
  union { unsigned u; float f; } v; v.u = ((unsigned)b) << 16;
  return v.f;
}

__device__ __forceinline__ void gl_lds16(const unsigned short* g, unsigned short* l) {
  __builtin_amdgcn_global_load_lds(
      (const __attribute__((address_space(1))) unsigned int*)g,
      (__attribute__((address_space(3))) unsigned int*)l, 16, 0, 0);
}

// ---------------------------------------------------------------------------
// k_score: single scores-GEMM pass (64M x 256N, K=224), LDS-staged B
// (round-0 inner loop — measured faster than direct-reg loads).
// Epilogue: stash bf16(v) to ws and accumulate S = sum(exp(v_bf16)) per row.
// XCD-swizzled 1-D grid of 1600: xb = id % 200 (skip >= 196), yb = id / 200.
// ---------------------------------------------------------------------------
__global__ __launch_bounds__(256, 4) void k_score(
    const unsigned short* __restrict__ Ap, const unsigned short* __restrict__ Bp,
    const float* __restrict__ mlp_b, unsigned short* __restrict__ stash,
    float* __restrict__ S_ws)
{
  __shared__ __align__(16) char buf[17408];
  const int id = blockIdx.x;
  const int yb = id / 200;
  const int xb = id - yb * 200;
  if (xb >= NXB) return;

  unsigned short* Bs = (unsigned short*)buf;
  float* red = (float*)(buf + 16384);
  const int tid = threadIdx.x;
  const int w = tid >> 6, lane = tid & 63;
  const int q = lane >> 4, l15 = lane & 15;
  const int mt0 = yb * 4;
  const int m0 = yb * 64;
  const int ntb = xb * 16 + w * 4;

  float bias[4];
  #pragma unroll
  for (int nl = 0; nl < 4; ++nl) {
    const int col = (ntb + nl) * 16 + l15;
    bias[nl] = (col < NUM_E) ? mlp_b[col] : 0.f;
  }
  const unsigned short* apBase = Ap + (size_t)mt0 * NKT * 512;

  f32x4 acc[4][4];
  #pragma unroll
  for (int i = 0; i < 4; i++)
    #pragma unroll
    for (int j = 0; j < 4; j++) acc[i][j] = (f32x4){0, 0, 0, 0};

  for (int kt = 0; kt < NKT; ++kt) {
    #pragma unroll
    for (int nl = 0; nl < 4; ++nl)
      gl_lds16(Bp + ((size_t)(ntb + nl) * NKT + kt) * 512 + lane * 8,
               &Bs[(w * 4 + nl) * 512]);
    s16x8 a[4];
    #pragma unroll
    for (int mi = 0; mi < 4; ++mi)
      a[mi] = *(const s16x8*)&apBase[((mi * NKT + kt) * 64 + lane) * 8];
    __syncthreads();
    s16x8 bfr[4];
    #pragma unroll
    for (int nl = 0; nl < 4; ++nl)
      bfr[nl] = *(const s16x8*)&Bs[((w * 4 + nl) * 64 + lane) * 8];
    #pragma unroll
    for (int nl = 0; nl < 4; ++nl)
      #pragma unroll
      for (int mi = 0; mi < 4; ++mi)
        acc[mi][nl] = __builtin_amdgcn_mfma_f32_16x16x32_bf16(a[mi], bfr[nl], acc[mi][nl], 0, 0, 0);
    __syncthreads();
  }

  // epilogue: stash bf16 scores + per-row exp-sum
  float rs[4][4];
  #pragma unroll
  for (int mi = 0; mi < 4; mi++)
    #pragma unroll
    for (int p = 0; p < 4; p++) rs[mi][p] = 0.f;
  #pragma unroll
  for (int mi = 0; mi < 4; ++mi)
    #pragma unroll
    for (int nl = 0; nl < 4; ++nl) {
      const int col = (ntb + nl) * 16 + l15;
      #pragma unroll
      for (int p = 0; p < 4; p++) {
        if (col < NUM_E) {
          const float v = acc[mi][nl][p] + bias[nl];
          const unsigned short vb = f2bf(v);
          const int row = m0 + mi * 16 + q * 4 + p;
          stash[(size_t)row * NUM_E + col] = vb;
          rs[mi][p] += __expf(bf2f(vb));
        }
      }
    }
  #pragma unroll
  for (int m = 1; m < 16; m <<= 1)
    for (int mi = 0; mi < 4; mi++)
      for (int p = 0; p < 4; p++)
        rs[mi][p] += __shfl_xor(rs[mi][p], m, 64);
  if (l15 == 0)
    for (int mi = 0; mi < 4; mi++)
      for (int p = 0; p < 4; p++)
        red[w * 64 + mi * 16 + q * 4 + p] = rs[mi][p];
  __syncthreads();
  if (tid < 64)
    atomicAdd(&S_ws[m0 + tid],
              red[tid] + red[64 + tid] + red[128 + tid] + red[192 + tid]);
}

// ---------------------------------------------------------------------------
// k_final: streaming finalize. out = log(exp(v)*invS + invD).
// Reads 51 MB bf16 stash, writes 102 MB f32 out — pure BW pass.
// ---------------------------------------------------------------------------
__global__ __launch_bounds__(256) void k_final(
    const unsigned short* __restrict__ stash,
    const float* __restrict__ D_ws, const float* __restrict__ S_ws,
    float* __restrict__ out)
{
  const int COLS8 = NUM_E / 8;           // 6250
  const int total = BATCH * COLS8;       // 3,200,000 units of 8 cols
  const int stride = gridDim.x * 256;
  for (int u = blockIdx.x * 256 + threadIdx.x; u < total; u += stride) {
    const int b = u / COLS8;
    const int c8 = u - b * COLS8;
    const float invD = 0.5f / D_ws[b];
    const float invS = 0.5f / S_ws[b];
    const size_t base = (size_t)b * NUM_E + (size_t)c8 * 8;
    const uint4 raw = *(const uint4*)(stash + base);
    float o[8];
    const unsigned wds[4] = {raw.x, raw.y, raw.z, raw.w};
    #pragma unroll
    for (int j = 0; j < 4; ++j) {
      const float v0 = bf2f((unsigned short)(wds[j] & 0xFFFF));
      const float v1 = bf2f((unsigned short)(wds[j] >> 16));
      o[2 * j]     = __logf(fmaf(__expf(v0), invS, invD));
      o[2 * j + 1] = __logf(fmaf(__expf(v1), invS, invD));
    }
    *(float4*)(out + base)     = make_float4(o[0], o[1], o[2], o[3]);
    *(float4*)(out + base + 4) = make_float4(o[4], o[5], o[6], o[7]);
  }
}

// ---------------------------------------------------------------------------
// Stage 1: grid = 512 batch blocks (fused xgemm+routing, one block per batch
// row) + 784 pack blocks (mlp_w -> Bp fragments) + 1 S-zero block.
// ---------------------------------------------------------------------------
__global__ __launch_bounds__(256, 3) void k_stage1(
    const int* __restrict__ idx, const int* __restrict__ times,
    const float* __restrict__ emb, const float* __restrict__ Ws_w,
    const float* __restrict__ Ws_b, const float* __restrict__ mlp_w,
    unsigned short* __restrict__ Bp, unsigned short* __restrict__ Ap,
    float* __restrict__ poses_f, float* __restrict__ expa_ws,
    float* __restrict__ D_ws, float* __restrict__ S_ws)
{
  __shared__ __align__(16) char buf[40320];
  __shared__ float cc[NN], bb[NN], vv[HID_DIM], red4[4], scaleS;
  __shared__ int sidx[NN];
  const int u = blockIdx.x;
  const int tid = threadIdx.x;
  const int w = tid >> 6, lane = tid & 63;
  const int q = lane >> 4, l15 = lane & 15;

  if (u < BATCH) {
    // ================= fused xgemm + routing for batch row u ==============
    const int b = u;
    if (tid < NN) {
      sidx[tid] = idx[b * NN + tid];
      bb[tid] = 2.0f / (1.0f + (float)times[b * NN + tid]);
    }
    __syncthreads();
    unsigned short* Afr = (unsigned short*)buf;            // 16384 B
    unsigned short* Bfr = (unsigned short*)(buf + 16384);  // 13312 B per kt
    // stage A fragments: 64 rows (>=NN zero) x 128 k, gather from emb
    for (int v = tid; v < 1024; v += 256) {
      const int row = v >> 4, c = v & 15;
      const int kt = c >> 2, qq = c & 3;
      unsigned short tmp[8] __attribute__((aligned(16)));
      if (row < NN) {
        const float* src = emb + (size_t)sidx[row] * EMBED_DIM + c * 8;
        float4 f0 = *(const float4*)src;
        float4 f1 = *(const float4*)(src + 4);
        tmp[0] = f2bf(f0.x); tmp[1] = f2bf(f0.y); tmp[2] = f2bf(f0.z); tmp[3] = f2bf(f0.w);
        tmp[4] = f2bf(f1.x); tmp[5] = f2bf(f1.y); tmp[6] = f2bf(f1.z); tmp[7] = f2bf(f1.w);
      } else {
        for (int j = 0; j < 8; j++) tmp[j] = 0;
      }
      *(uint4*)&Afr[(((row >> 4) * 4 + kt) * 64 + qq * 16 + (row & 15)) * 8] = *(uint4*)tmp;
    }
    f32x4 acc[4][4];
    #pragma unroll
    for (int i = 0; i < 4; i++)
      #pragma unroll
      for (int j = 0; j < 4; j++) acc[i][j] = (f32x4){0, 0, 0, 0};
    __syncthreads();
    for (int kt = 0; kt < 4; ++kt) {
      // stage B kt-slice: 208 n (>=HID zero) x 32 k from Ws_w
      for (int v = tid; v < 832; v += 256) {
        const int n = v >> 2, cq = v & 3;
        unsigned short tmp[8] __attribute__((aligned(16)));
        if (n < HID_DIM) {
          const float* src = Ws_w + (size_t)n * EMBED_DIM + kt * 32 + cq * 8;
          float4 f0 = *(const float4*)src;
          float4 f1 = *(const float4*)(src + 4);
          tmp[0] = f2bf(f0.x); tmp[1] = f2bf(f0.y); tmp[2] = f2bf(f0.z); tmp[3] = f2bf(f0.w);
          tmp[4] = f2bf(f1.x); tmp[5] = f2bf(f1.y); tmp[6] = f2bf(f1.z); tmp[7] = f2bf(f1.w);
        } else {
          for (int j = 0; j < 8; j++) tmp[j] = 0;
        }
        *(uint4*)&Bfr[((n >> 4) * 64 + cq * 16 + (n & 15)) * 8] = *(uint4*)tmp;
      }
      __syncthreads();
      s16x8 a[4];
      #pragma unroll
      for (int mt = 0; mt < 4; ++mt)
        a[mt] = *(const s16x8*)&Afr[((mt * 4 + kt) * 64 + lane) * 8];
      #pragma unroll
      for (int ii = 0; ii < 4; ++ii) {
        const int nt = w + ii * 4;
        if (nt < 13) {
          s16x8 bv = *(const s16x8*)&Bfr[(nt * 64 + lane) * 8];
          #pragma unroll
          for (int mt = 0; mt < 4; ++mt)
            acc[mt][ii] = __builtin_amdgcn_mfma_f32_16x16x32_bf16(a[mt], bv, acc[mt][ii], 0, 0, 0);
        }
      }
      __syncthreads();
    }
    // epilogue: x = acc + Ws_b into u-matrix (fp32, overlays frag LDS)
    float* uu = (float*)buf;
    #pragma unroll
    for (int ii = 0; ii < 4; ++ii) {
      const int nt = w + ii * 4;
      if (nt < 13) {
        const int col = nt * 16 + l15;
        if (col < HID_DIM) {
          const float bv = Ws_b[col];
          #pragma unroll
          for (int mt = 0; mt < 4; ++mt)
            #pragma unroll
            for (int p = 0; p < 4; p++) {
              const int row = mt * 16 + q * 4 + p;
              if (row < NN) uu[row * USTRIDE + col] = acc[mt][ii][p] + bv;
            }
        }
      }
    }
    __syncthreads();
    // L2-normalize rows (4 threads/row)
    const int un = tid >> 2, uc0 = (tid & 3) * 50;
    if (un < NN) {
      float s = 0.f;
      for (int j = 0; j < 50; j++) {
        const float x = uu[un * USTRIDE + uc0 + j];
        s += x * x;
      }
      s += __shfl_xor(s, 1, 64);
      s += __shfl_xor(s, 2, 64);
      const float inv = 1.0f / fmaxf(sqrtf(s), 1e-12f);
      for (int j = 0; j < 50; j++) uu[un * USTRIDE + uc0 + j] *= inv;
    }
    __syncthreads();
    // dynamic routing, 3 iters
    for (int it = 0; it < 3; ++it) {
      if (tid < 64) {
        float x = (tid < NN) ? bb[tid] : -1e30f;
        float m = x;
        for (int d = 1; d < 64; d <<= 1) m = fmaxf(m, __shfl_xor(m, d, 64));
        float e = (tid < NN) ? __expf(x - m) : 0.f;
        float s = e;
        for (int d = 1; d < 64; d <<= 1) s += __shfl_xor(s, d, 64);
        if (tid < NN) cc[tid] = e * (float)NN / s;
      }
      __syncthreads();
      float sh = 0.f;
      if (tid < HID_DIM)
        for (int n = 0; n < NN; n++) sh += cc[n] * uu[n * USTRIDE + tid];
      float sq2 = (tid < HID_DIM) ? sh * sh : 0.f;
      for (int d = 1; d < 64; d <<= 1) sq2 += __shfl_xor(sq2, d, 64);
      if ((tid & 63) == 0) red4[tid >> 6] = sq2;
      __syncthreads();
      if (tid == 0) {
        const float t2 = red4[0] + red4[1] + red4[2] + red4[3];
        scaleS = t2 / (1.0f + t2) / sqrtf(t2 + 1e-9f);
      }
      __syncthreads();
      if (tid < HID_DIM) vv[tid] = scaleS * sh;
      __syncthreads();
      if (it < 2) {
        float d = 0.f;
        if (un < NN)
          for (int j = 0; j < 50; j++)
            d += uu[un * USTRIDE + uc0 + j] * vv[uc0 + j];
        d += __shfl_xor(d, 1, 64);
        d += __shfl_xor(d, 2, 64);
        if (un < NN && (tid & 3) == 0) bb[un] += d;
        __syncthreads();
      }
    }
    // outputs: Ap fragments, fp32 poses, expa, D_b
    if (tid < KPAD) {
      const float val = (tid < HID_DIM) ? vv[tid] : 0.f;
      const int kt = tid >> 5, rem = tid & 31, qq = rem >> 3, j = rem & 7;
      const int mt = b >> 4, ll = b & 15;
      Ap[(size_t)(((mt * NKT + kt) * 64) + qq * 16 + ll) * 8 + j] = f2bf(val);
    }
    if (tid < HID_DIM) poses_f[b * HID_DIM + tid] = vv[tid];
    if (tid < 64) {
      float a2 = 0.f; int first = 1;
      const int my = (tid < NN) ? sidx[tid] : -1;
      if (tid < NN) {
        for (int n = 0; n < NN; n++)
          if (sidx[n] == my) { a2 += cc[n]; if (n < tid) first = 0; }
        expa_ws[b * NN + tid] = __expf(a2);
      }
      float contrib = (tid < NN && first) ? (__expf(a2) - 1.0f) : 0.f;
      for (int d = 1; d < 64; d <<= 1) contrib += __shfl_xor(contrib, d, 64);
      if (tid == 0) D_ws[b] = (float)NUM_E + contrib;
    }
  } else if (u < BATCH + PACK_UNITS) {
    // ================= coalesced pack of 4 n-tiles into Bp =================
    const int pb = u - BATCH;
    unsigned short* smem = (unsigned short*)buf;
    const size_t base_f = (size_t)pb * 64 * HID_DIM;
    const float4* src4 = (const float4*)(mlp_w + base_f);
    for (int i = tid; i < 3200; i += 256) {
      float4 f;
      if (base_f + 4 * (size_t)i + 4 <= (size_t)NUM_E * HID_DIM) f = src4[i];
      else f = make_float4(0.f, 0.f, 0.f, 0.f);
      unsigned short t4[4] __attribute__((aligned(8))) = {
        f2bf(f.x), f2bf(f.y), f2bf(f.z), f2bf(f.w)};
      *(uint2*)&smem[i * 4] = *(uint2*)t4;
    }
    __syncthreads();
    const int nt0 = pb * 4;
    unsigned short* dst = Bp + (size_t)nt0 * NKT * 512;
    for (int s2 = 0; s2 < 7; ++s2) {
      const int fi = s2 * 256 + tid;
      const int fr = fi >> 6;
      const int ln = fi & 63;
      const int nt_l = fr / 7, kt = fr - nt_l * 7;
      const int r = nt_l * 16 + (ln & 15);
      const int kb = kt * 32 + (ln >> 4) * 8;
      uint4 val;
      if (kb < HID_DIM) val = *(const uint4*)&smem[r * HID_DIM + kb];
      else val = make_uint4(0, 0, 0, 0);
      *(uint4*)&dst[(size_t)fi * 8] = val;
    }
  } else {
    S_ws[tid] = 0.f;
    S_ws[256 + tid] = 0.f;
  }
}

// ---------------------------------------------------------------------------
// Kernel D: fixup history positions; recompute score via fp32 dot product.
// ---------------------------------------------------------------------------
__global__ __launch_bounds__(256) void k_fix(
    const int* __restrict__ idx, const float* __restrict__ expa,
    const float* __restrict__ poses_f, const float* __restrict__ mlp_w,
    const float* __restrict__ mlp_b, const float* __restrict__ D_ws,
    const float* __restrict__ S_ws, float* __restrict__ out)
{
  const int t = blockIdx.x * 4 + (threadIdx.x >> 6);
  const int lane = threadIdx.x & 63;
  if (t >= BATCH * NN) return;
  const int b = t / NN;
  const int j = idx[t];
  float dot = 0.f;
  for (int h = lane; h < HID_DIM; h += 64)
    dot += poses_f[b * HID_DIM + h] * mlp_w[(size_t)j * HID_DIM + h];
  for (int m = 1; m < 64; m <<= 1) dot += __shfl_xor(dot, m, 64);
  if (lane == 0) {
    const float s = dot + mlp_b[j];
    out[(size_t)b * NUM_E + j] = __logf(0.5f * expa[t] / D_ws[b] +
                                        0.5f * __expf(s) / S_ws[b]);
  }
}

extern "C" void kernel_launch(void* const* d_in, const int* in_sizes, int n_in,
                              void* d_out, int out_size, void* d_ws, size_t ws_size,
                              hipStream_t stream) {
  const int*   idx   = (const int*)d_in[0];
  const int*   times = (const int*)d_in[1];
  const float* emb   = (const float*)d_in[2];
  const float* Ws_w  = (const float*)d_in[3];
  const float* Ws_b  = (const float*)d_in[4];
  const float* mlp_w = (const float*)d_in[5];
  const float* mlp_b = (const float*)d_in[6];
  float* out = (float*)d_out;

  char* ws = (char*)d_ws;
  unsigned short* Bp    = (unsigned short*)ws; ws += (size_t)NTT2 * NKT * 64 * 8 * 2;  // 22.5 MB
  unsigned short* Ap    = (unsigned short*)ws; ws += (size_t)32 * NKT * 64 * 8 * 2;    // 229 KB
  float* poses_f        = (float*)ws;          ws += (size_t)BATCH * HID_DIM * 4;      // 410 KB
  float* expa           = (float*)ws;          ws += (size_t)BATCH * NN * 4;           // 102 KB
  float* D_ws           = (float*)ws;          ws += (size_t)BATCH * 4;
  float* S_ws           = (float*)ws;          ws += (size_t)BATCH * 4;
  unsigned short* stash = (unsigned short*)ws; ws += (size_t)BATCH * NUM_E * 2;        // 51.2 MB

  k_stage1 <<<dim3(BATCH + PACK_UNITS + 1), 256, 0, stream>>>(
      idx, times, emb, Ws_w, Ws_b, mlp_w, Bp, Ap, poses_f, expa, D_ws, S_ws);
  k_score  <<<dim3(1600), 256, 0, stream>>>(Ap, Bp, mlp_b, stash, S_ws);
  k_final  <<<dim3(2048), 256, 0, stream>>>(stash, D_ws, S_ws, out);
  k_fix    <<<dim3(BATCH * NN / 4), 256, 0, stream>>>(idx, expa, poses_f, mlp_w, mlp_b, D_ws, S_ws, out);
}

// Round 4
// 250.225 us; speedup vs baseline: 1.0767x; 1.0597x over previous
//
#include <hip/hip_runtime.h>
#include <stdint.h>

#define NUM_E 50000
#define EMBED_DIM 128
#define HID_DIM 200
#define BATCH 512
#define NN 50
#define KPAD 224
#define NKT 7      // K tiles of 32 for scores GEMM
#define NTT2 3136  // N fragment tiles padded: 3136*16 = 50176 = 196*256
#define NXB 196
#define PACK_UNITS 784
#define USTRIDE 201

typedef short s16x8 __attribute__((ext_vector_type(8)));
typedef float f32x4 __attribute__((ext_vector_type(4)));

__device__ inline unsigned short f2bf(float f) {
  union { float f; unsigned u; } v; v.f = f;
  unsigned r = v.u + 0x7FFF + ((v.u >> 16) & 1);
  return (unsigned short)(r >> 16);
}
__device__ inline float bf2f(unsigned short b) {
  union { unsigned u; float f; } v; v.u = ((unsigned)b) << 16;
  return v.f;
}

__device__ __forceinline__ void gl_lds16(const unsigned short* g, unsigned short* l) {
  __builtin_amdgcn_global_load_lds(
      (const __attribute__((address_space(1))) unsigned int*)g,
      (__attribute__((address_space(3))) unsigned int*)l, 16, 0, 0);
}

// ---------------------------------------------------------------------------
// k_score: single scores-GEMM pass (64M x 256N, K=224), 2-phase double-
// buffered LDS staging (T3 minimum recipe): STAGE(kt+1) + A-prefetch overlap
// ds_read+MFMA of kt; one __syncthreads (vmcnt0+barrier) per iteration.
// Epilogue: stash bf16(v) to ws and accumulate S = sum(exp(v_bf16)) per row.
// XCD-swizzled 1-D grid of 1600: xb = id % 200 (skip >= 196), yb = id / 200.
// ---------------------------------------------------------------------------
__global__ __launch_bounds__(256, 4) void k_score(
    const unsigned short* __restrict__ Ap, const unsigned short* __restrict__ Bp,
    const float* __restrict__ mlp_b, unsigned short* __restrict__ stash,
    float* __restrict__ S_ws)
{
  __shared__ __align__(16) unsigned short Bs[2][8192];  // 2 x 16 KB
  __shared__ float red[256];
  const int id = blockIdx.x;
  const int yb = id / 200;
  const int xb = id - yb * 200;
  if (xb >= NXB) return;

  const int tid = threadIdx.x;
  const int w = tid >> 6, lane = tid & 63;
  const int q = lane >> 4, l15 = lane & 15;
  const int mt0 = yb * 4;
  const int m0 = yb * 64;
  const int ntb = xb * 16 + w * 4;

  float bias[4];
  #pragma unroll
  for (int nl = 0; nl < 4; ++nl) {
    const int col = (ntb + nl) * 16 + l15;
    bias[nl] = (col < NUM_E) ? mlp_b[col] : 0.f;
  }
  const unsigned short* apB = Ap + (size_t)mt0 * NKT * 512 + (size_t)lane * 8;
  const unsigned short* bpB = Bp + (size_t)ntb * NKT * 512 + (size_t)lane * 8;

  f32x4 acc[4][4];
  #pragma unroll
  for (int i = 0; i < 4; i++)
    #pragma unroll
    for (int j = 0; j < 4; j++) acc[i][j] = (f32x4){0, 0, 0, 0};

  s16x8 areg[2][4];

  // prologue: stage kt=0 into Bs[0]; prefetch A-frags for kt=0
  #pragma unroll
  for (int nl = 0; nl < 4; ++nl)
    gl_lds16(bpB + (size_t)nl * NKT * 512, &Bs[0][(w * 4 + nl) * 512]);
  #pragma unroll
  for (int mi = 0; mi < 4; ++mi)
    areg[0][mi] = *(const s16x8*)(apB + (size_t)(mi * NKT) * 512);
  __syncthreads();

  #pragma unroll
  for (int kt = 0; kt < NKT; ++kt) {
    const int cur = kt & 1;
    if (kt < NKT - 1) {
      // stage next tile + prefetch next A-frags (overlaps this tile's MFMA)
      #pragma unroll
      for (int nl = 0; nl < 4; ++nl)
        gl_lds16(bpB + (size_t)(nl * NKT + kt + 1) * 512,
                 &Bs[cur ^ 1][(w * 4 + nl) * 512]);
      #pragma unroll
      for (int mi = 0; mi < 4; ++mi)
        areg[cur ^ 1][mi] = *(const s16x8*)(apB + (size_t)(mi * NKT + kt + 1) * 512);
    }
    s16x8 bfr[4];
    #pragma unroll
    for (int nl = 0; nl < 4; ++nl)
      bfr[nl] = *(const s16x8*)&Bs[cur][((w * 4 + nl) * 64 + lane) * 8];
    #pragma unroll
    for (int nl = 0; nl < 4; ++nl)
      #pragma unroll
      for (int mi = 0; mi < 4; ++mi)
        acc[mi][nl] = __builtin_amdgcn_mfma_f32_16x16x32_bf16(areg[cur][mi], bfr[nl], acc[mi][nl], 0, 0, 0);
    if (kt < NKT - 1) __syncthreads();  // drains this iter's stage; aligns buffers
  }

  // epilogue: stash bf16 scores + per-row exp-sum
  float rs[4][4];
  #pragma unroll
  for (int mi = 0; mi < 4; mi++)
    #pragma unroll
    for (int p = 0; p < 4; p++) rs[mi][p] = 0.f;
  #pragma unroll
  for (int mi = 0; mi < 4; ++mi)
    #pragma unroll
    for (int nl = 0; nl < 4; ++nl) {
      const int col = (ntb + nl) * 16 + l15;
      #pragma unroll
      for (int p = 0; p < 4; p++) {
        if (col < NUM_E) {
          const float v = acc[mi][nl][p] + bias[nl];
          const unsigned short vb = f2bf(v);
          const int row = m0 + mi * 16 + q * 4 + p;
          stash[(size_t)row * NUM_E + col] = vb;
          rs[mi][p] += __expf(bf2f(vb));
        }
      }
    }
  #pragma unroll
  for (int m = 1; m < 16; m <<= 1)
    for (int mi = 0; mi < 4; mi++)
      for (int p = 0; p < 4; p++)
        rs[mi][p] += __shfl_xor(rs[mi][p], m, 64);
  __syncthreads();  // Bs reads long done; reuse-safe before red[] writes
  if (l15 == 0)
    for (int mi = 0; mi < 4; mi++)
      for (int p = 0; p < 4; p++)
        red[w * 64 + mi * 16 + q * 4 + p] = rs[mi][p];
  __syncthreads();
  if (tid < 64)
    atomicAdd(&S_ws[m0 + tid],
              red[tid] + red[64 + tid] + red[128 + tid] + red[192 + tid]);
}

// ---------------------------------------------------------------------------
// k_final: streaming finalize. out = log(exp(v)*invS + invD).
// Reads 51 MB bf16 stash, writes 102 MB f32 out — pure BW pass.
// ---------------------------------------------------------------------------
__global__ __launch_bounds__(256) void k_final(
    const unsigned short* __restrict__ stash,
    const float* __restrict__ D_ws, const float* __restrict__ S_ws,
    float* __restrict__ out)
{
  const int COLS8 = NUM_E / 8;           // 6250
  const int total = BATCH * COLS8;       // 3,200,000 units of 8 cols
  const int stride = gridDim.x * 256;
  for (int u = blockIdx.x * 256 + threadIdx.x; u < total; u += stride) {
    const int b = u / COLS8;
    const int c8 = u - b * COLS8;
    const float invD = 0.5f / D_ws[b];
    const float invS = 0.5f / S_ws[b];
    const size_t base = (size_t)b * NUM_E + (size_t)c8 * 8;
    const uint4 raw = *(const uint4*)(stash + base);
    float o[8];
    const unsigned wds[4] = {raw.x, raw.y, raw.z, raw.w};
    #pragma unroll
    for (int j = 0; j < 4; ++j) {
      const float v0 = bf2f((unsigned short)(wds[j] & 0xFFFF));
      const float v1 = bf2f((unsigned short)(wds[j] >> 16));
      o[2 * j]     = __logf(fmaf(__expf(v0), invS, invD));
      o[2 * j + 1] = __logf(fmaf(__expf(v1), invS, invD));
    }
    *(float4*)(out + base)     = make_float4(o[0], o[1], o[2], o[3]);
    *(float4*)(out + base + 4) = make_float4(o[4], o[5], o[6], o[7]);
  }
}

// ---------------------------------------------------------------------------
// Stage 1: grid = 512 batch blocks (fused xgemm+routing, one block per batch
// row) + 784 pack blocks (mlp_w -> Bp fragments) + 1 S-zero block.
// ---------------------------------------------------------------------------
__global__ __launch_bounds__(256, 3) void k_stage1(
    const int* __restrict__ idx, const int* __restrict__ times,
    const float* __restrict__ emb, const float* __restrict__ Ws_w,
    const float* __restrict__ Ws_b, const float* __restrict__ mlp_w,
    unsigned short* __restrict__ Bp, unsigned short* __restrict__ Ap,
    float* __restrict__ poses_f, float* __restrict__ expa_ws,
    float* __restrict__ D_ws, float* __restrict__ S_ws)
{
  __shared__ __align__(16) char buf[40320];
  __shared__ float cc[NN], bb[NN], vv[HID_DIM], red4[4], scaleS;
  __shared__ int sidx[NN];
  const int u = blockIdx.x;
  const int tid = threadIdx.x;
  const int w = tid >> 6, lane = tid & 63;
  const int q = lane >> 4, l15 = lane & 15;

  if (u < BATCH) {
    // ================= fused xgemm + routing for batch row u ==============
    const int b = u;
    if (tid < NN) {
      sidx[tid] = idx[b * NN + tid];
      bb[tid] = 2.0f / (1.0f + (float)times[b * NN + tid]);
    }
    __syncthreads();
    unsigned short* Afr = (unsigned short*)buf;            // 16384 B
    unsigned short* Bfr = (unsigned short*)(buf + 16384);  // 13312 B per kt
    // stage A fragments: 64 rows (>=NN zero) x 128 k, gather from emb
    for (int v = tid; v < 1024; v += 256) {
      const int row = v >> 4, c = v & 15;
      const int kt = c >> 2, qq = c & 3;
      unsigned short tmp[8] __attribute__((aligned(16)));
      if (row < NN) {
        const float* src = emb + (size_t)sidx[row] * EMBED_DIM + c * 8;
        float4 f0 = *(const float4*)src;
        float4 f1 = *(const float4*)(src + 4);
        tmp[0] = f2bf(f0.x); tmp[1] = f2bf(f0.y); tmp[2] = f2bf(f0.z); tmp[3] = f2bf(f0.w);
        tmp[4] = f2bf(f1.x); tmp[5] = f2bf(f1.y); tmp[6] = f2bf(f1.z); tmp[7] = f2bf(f1.w);
      } else {
        for (int j = 0; j < 8; j++) tmp[j] = 0;
      }
      *(uint4*)&Afr[(((row >> 4) * 4 + kt) * 64 + qq * 16 + (row & 15)) * 8] = *(uint4*)tmp;
    }
    f32x4 acc[4][4];
    #pragma unroll
    for (int i = 0; i < 4; i++)
      #pragma unroll
      for (int j = 0; j < 4; j++) acc[i][j] = (f32x4){0, 0, 0, 0};
    __syncthreads();
    for (int kt = 0; kt < 4; ++kt) {
      // stage B kt-slice: 208 n (>=HID zero) x 32 k from Ws_w
      for (int v = tid; v < 832; v += 256) {
        const int n = v >> 2, cq = v & 3;
        unsigned short tmp[8] __attribute__((aligned(16)));
        if (n < HID_DIM) {
          const float* src = Ws_w + (size_t)n * EMBED_DIM + kt * 32 + cq * 8;
          float4 f0 = *(const float4*)src;
          float4 f1 = *(const float4*)(src + 4);
          tmp[0] = f2bf(f0.x); tmp[1] = f2bf(f0.y); tmp[2] = f2bf(f0.z); tmp[3] = f2bf(f0.w);
          tmp[4] = f2bf(f1.x); tmp[5] = f2bf(f1.y); tmp[6] = f2bf(f1.z); tmp[7] = f2bf(f1.w);
        } else {
          for (int j = 0; j < 8; j++) tmp[j] = 0;
        }
        *(uint4*)&Bfr[((n >> 4) * 64 + cq * 16 + (n & 15)) * 8] = *(uint4*)tmp;
      }
      __syncthreads();
      s16x8 a[4];
      #pragma unroll
      for (int mt = 0; mt < 4; ++mt)
        a[mt] = *(const s16x8*)&Afr[((mt * 4 + kt) * 64 + lane) * 8];
      #pragma unroll
      for (int ii = 0; ii < 4; ++ii) {
        const int nt = w + ii * 4;
        if (nt < 13) {
          s16x8 bv = *(const s16x8*)&Bfr[(nt * 64 + lane) * 8];
          #pragma unroll
          for (int mt = 0; mt < 4; ++mt)
            acc[mt][ii] = __builtin_amdgcn_mfma_f32_16x16x32_bf16(a[mt], bv, acc[mt][ii], 0, 0, 0);
        }
      }
      __syncthreads();
    }
    // epilogue: x = acc + Ws_b into u-matrix (fp32, overlays frag LDS)
    float* uu = (float*)buf;
    #pragma unroll
    for (int ii = 0; ii < 4; ++ii) {
      const int nt = w + ii * 4;
      if (nt < 13) {
        const int col = nt * 16 + l15;
        if (col < HID_DIM) {
          const float bv = Ws_b[col];
          #pragma unroll
          for (int mt = 0; mt < 4; ++mt)
            #pragma unroll
            for (int p = 0; p < 4; p++) {
              const int row = mt * 16 + q * 4 + p;
              if (row < NN) uu[row * USTRIDE + col] = acc[mt][ii][p] + bv;
            }
        }
      }
    }
    __syncthreads();
    // L2-normalize rows (4 threads/row)
    const int un = tid >> 2, uc0 = (tid & 3) * 50;
    if (un < NN) {
      float s = 0.f;
      for (int j = 0; j < 50; j++) {
        const float x = uu[un * USTRIDE + uc0 + j];
        s += x * x;
      }
      s += __shfl_xor(s, 1, 64);
      s += __shfl_xor(s, 2, 64);
      const float inv = 1.0f / fmaxf(sqrtf(s), 1e-12f);
      for (int j = 0; j < 50; j++) uu[un * USTRIDE + uc0 + j] *= inv;
    }
    __syncthreads();
    // dynamic routing, 3 iters
    for (int it = 0; it < 3; ++it) {
      if (tid < 64) {
        float x = (tid < NN) ? bb[tid] : -1e30f;
        float m = x;
        for (int d = 1; d < 64; d <<= 1) m = fmaxf(m, __shfl_xor(m, d, 64));
        float e = (tid < NN) ? __expf(x - m) : 0.f;
        float s = e;
        for (int d = 1; d < 64; d <<= 1) s += __shfl_xor(s, d, 64);
        if (tid < NN) cc[tid] = e * (float)NN / s;
      }
      __syncthreads();
      float sh = 0.f;
      if (tid < HID_DIM)
        for (int n = 0; n < NN; n++) sh += cc[n] * uu[n * USTRIDE + tid];
      float sq2 = (tid < HID_DIM) ? sh * sh : 0.f;
      for (int d = 1; d < 64; d <<= 1) sq2 += __shfl_xor(sq2, d, 64);
      if ((tid & 63) == 0) red4[tid >> 6] = sq2;
      __syncthreads();
      if (tid == 0) {
        const float t2 = red4[0] + red4[1] + red4[2] + red4[3];
        scaleS = t2 / (1.0f + t2) / sqrtf(t2 + 1e-9f);
      }
      __syncthreads();
      if (tid < HID_DIM) vv[tid] = scaleS * sh;
      __syncthreads();
      if (it < 2) {
        float d = 0.f;
        if (un < NN)
          for (int j = 0; j < 50; j++)
            d += uu[un * USTRIDE + uc0 + j] * vv[uc0 + j];
        d += __shfl_xor(d, 1, 64);
        d += __shfl_xor(d, 2, 64);
        if (un < NN && (tid & 3) == 0) bb[un] += d;
        __syncthreads();
      }
    }
    // outputs: Ap fragments, fp32 poses, expa, D_b
    if (tid < KPAD) {
      const float val = (tid < HID_DIM) ? vv[tid] : 0.f;
      const int kt = tid >> 5, rem = tid & 31, qq = rem >> 3, j = rem & 7;
      const int mt = b >> 4, ll = b & 15;
      Ap[(size_t)(((mt * NKT + kt) * 64) + qq * 16 + ll) * 8 + j] = f2bf(val);
    }
    if (tid < HID_DIM) poses_f[b * HID_DIM + tid] = vv[tid];
    if (tid < 64) {
      float a2 = 0.f; int first = 1;
      const int my = (tid < NN) ? sidx[tid] : -1;
      if (tid < NN) {
        for (int n = 0; n < NN; n++)
          if (sidx[n] == my) { a2 += cc[n]; if (n < tid) first = 0; }
        expa_ws[b * NN + tid] = __expf(a2);
      }
      float contrib = (tid < NN && first) ? (__expf(a2) - 1.0f) : 0.f;
      for (int d = 1; d < 64; d <<= 1) contrib += __shfl_xor(contrib, d, 64);
      if (tid == 0) D_ws[b] = (float)NUM_E + contrib;
    }
  } else if (u < BATCH + PACK_UNITS) {
    // ================= coalesced pack of 4 n-tiles into Bp =================
    const int pb = u - BATCH;
    unsigned short* smem = (unsigned short*)buf;
    const size_t base_f = (size_t)pb * 64 * HID_DIM;
    const float4* src4 = (const float4*)(mlp_w + base_f);
    for (int i = tid; i < 3200; i += 256) {
      float4 f;
      if (base_f + 4 * (size_t)i + 4 <= (size_t)NUM_E * HID_DIM) f = src4[i];
      else f = make_float4(0.f, 0.f, 0.f, 0.f);
      unsigned short t4[4] __attribute__((aligned(8))) = {
        f2bf(f.x), f2bf(f.y), f2bf(f.z), f2bf(f.w)};
      *(uint2*)&smem[i * 4] = *(uint2*)t4;
    }
    __syncthreads();
    const int nt0 = pb * 4;
    unsigned short* dst = Bp + (size_t)nt0 * NKT * 512;
    for (int s2 = 0; s2 < 7; ++s2) {
      const int fi = s2 * 256 + tid;
      const int fr = fi >> 6;
      const int ln = fi & 63;
      const int nt_l = fr / 7, kt = fr - nt_l * 7;
      const int r = nt_l * 16 + (ln & 15);
      const int kb = kt * 32 + (ln >> 4) * 8;
      uint4 val;
      if (kb < HID_DIM) val = *(const uint4*)&smem[r * HID_DIM + kb];
      else val = make_uint4(0, 0, 0, 0);
      *(uint4*)&dst[(size_t)fi * 8] = val;
    }
  } else {
    S_ws[tid] = 0.f;
    S_ws[256 + tid] = 0.f;
  }
}

// ---------------------------------------------------------------------------
// Kernel D: fixup history positions; recompute score via fp32 dot product.
// ---------------------------------------------------------------------------
__global__ __launch_bounds__(256) void k_fix(
    const int* __restrict__ idx, const float* __restrict__ expa,
    const float* __restrict__ poses_f, const float* __restrict__ mlp_w,
    const float* __restrict__ mlp_b, const float* __restrict__ D_ws,
    const float* __restrict__ S_ws, float* __restrict__ out)
{
  const int t = blockIdx.x * 4 + (threadIdx.x >> 6);
  const int lane = threadIdx.x & 63;
  if (t >= BATCH * NN) return;
  const int b = t / NN;
  const int j = idx[t];
  float dot = 0.f;
  for (int h = lane; h < HID_DIM; h += 64)
    dot += poses_f[b * HID_DIM + h] * mlp_w[(size_t)j * HID_DIM + h];
  for (int m = 1; m < 64; m <<= 1) dot += __shfl_xor(dot, m, 64);
  if (lane == 0) {
    const float s = dot + mlp_b[j];
    out[(size_t)b * NUM_E + j] = __logf(0.5f * expa[t] / D_ws[b] +
                                        0.5f * __expf(s) / S_ws[b]);
  }
}

extern "C" void kernel_launch(void* const* d_in, const int* in_sizes, int n_in,
                              void* d_out, int out_size, void* d_ws, size_t ws_size,
                              hipStream_t stream) {
  const int*   idx   = (const int*)d_in[0];
  const int*   times = (const int*)d_in[1];
  const float* emb   = (const float*)d_in[2];
  const float* Ws_w  = (const float*)d_in[3];
  const float* Ws_b  = (const float*)d_in[4];
  const float* mlp_w = (const float*)d_in[5];
  const float* mlp_b = (const float*)d_in[6];
  float* out = (float*)d_out;

  char* ws = (char*)d_ws;
  unsigned short* Bp    = (unsigned short*)ws; ws += (size_t)NTT2 * NKT * 64 * 8 * 2;  // 22.5 MB
  unsigned short* Ap    = (unsigned short*)ws; ws += (size_t)32 * NKT * 64 * 8 * 2;    // 229 KB
  float* poses_f        = (float*)ws;          ws += (size_t)BATCH * HID_DIM * 4;      // 410 KB
  float* expa           = (float*)ws;          ws += (size_t)BATCH * NN * 4;           // 102 KB
  float* D_ws           = (float*)ws;          ws += (size_t)BATCH * 4;
  float* S_ws           = (float*)ws;          ws += (size_t)BATCH * 4;
  unsigned short* stash = (unsigned short*)ws; ws += (size_t)BATCH * NUM_E * 2;        // 51.2 MB

  k_stage1 <<<dim3(BATCH + PACK_UNITS + 1), 256, 0, stream>>>(
      idx, times, emb, Ws_w, Ws_b, mlp_w, Bp, Ap, poses_f, expa, D_ws, S_ws);
  k_score  <<<dim3(1600), 256, 0, stream>>>(Ap, Bp, mlp_b, stash, S_ws);
  k_final  <<<dim3(2048), 256, 0, stream>>>(stash, D_ws, S_ws, out);
  k_fix    <<<dim3(BATCH * NN / 4), 256, 0, stream>>>(idx, expa, poses_f, mlp_w, mlp_b, D_ws, S_ws, out);
}